// Round 6
// baseline (629.137 us; speedup 1.0000x reference)
//
#include <hip/hip_runtime.h>
#include <hip/hip_bf16.h>
#include <hip/hip_fp16.h>
#include <math.h>

#define NATOMS 16384
#define NEDGE  524288
#define NINT   6
#define NGAUSS 50
#define TK     2048
#define INV_DT 128.0f    // knots at d = k/128, range [0,16)
#define DT     (1.0f/128.0f)
#define LOG2F_ 0.69314718055994530942f
#define NBUCK  512       // per graph, 32 dst atoms each

typedef _Float16 h2 __attribute__((ext_vector_type(2)));

__device__ __forceinline__ float sspf(float v){
    return fmaxf(v, 0.f) + log1pf(__expf(-fabsf(v))) - LOG2F_;
}

// ---------------- h = emb[z]  (rows 0..N-1 = A, N..2N-1 = G)
__global__ __launch_bounds__(256) void k_embed(const int* __restrict__ zA, const int* __restrict__ zG,
                                               const float* __restrict__ emb, float* __restrict__ h){
    int idx = blockIdx.x * 256 + threadIdx.x;        // < 2*NATOMS*64
    int n = idx >> 6, f = idx & 63;
    int z = (n < NATOMS) ? zA[n] : zG[n - NATOMS];
    h[idx] = emb[(z << 6) + f];
}

// ---------------- bucket histogram (LDS-privatized, coalesced global adds)
__global__ __launch_bounds__(256) void k_bhist(const int* __restrict__ edgeA, const int* __restrict__ edgeG,
                                               int* __restrict__ bhist){
    __shared__ int lh[NBUCK];
    int blk = blockIdx.x;                    // 256: 0-127 graph A, 128-255 graph G
    int g   = blk >> 7;
    int e0  = (blk & 127) * 4096;
    const int* dst = (g ? edgeG : edgeA) + NEDGE;
    int t = threadIdx.x;
    lh[t] = 0; lh[t + 256] = 0;
    __syncthreads();
    #pragma unroll
    for (int j = 0; j < 16; j++){
        int d = dst[e0 + j * 256 + t];
        atomicAdd(&lh[d >> 5], 1);
    }
    __syncthreads();
    atomicAdd(&bhist[g * NBUCK + t],       lh[t]);
    atomicAdd(&bhist[g * NBUCK + 256 + t], lh[t + 256]);
}

// ---------------- bucket exclusive scan -> bstart (513/graph) + gcur init
__global__ __launch_bounds__(512) void k_bscan(const int* __restrict__ bhist, int* __restrict__ bstart,
                                               int* __restrict__ gcur){
    int g = blockIdx.x;
    __shared__ int s[NBUCK];
    int t = threadIdx.x;
    int v = bhist[g * NBUCK + t];
    s[t] = v;
    __syncthreads();
    for (int off = 1; off < NBUCK; off <<= 1){
        int a = (t >= off) ? s[t - off] : 0;
        __syncthreads();
        s[t] += a;
        __syncthreads();
    }
    int ex = s[t] - v;
    bstart[g * (NBUCK + 1) + t] = ex;
    gcur[g * NBUCK + t] = ex;
    if (t == NBUCK - 1) bstart[g * (NBUCK + 1) + NBUCK] = s[NBUCK - 1];
}

// ---------------- pass 1: bucket-binned placement (coherent writes)
// meta8: m.x = src(14) | ti<<14(11) | dstlow<<25(5) ; m.y = tf (fp32)
__global__ __launch_bounds__(256) void k_place1(const int* __restrict__ edgeA, const int* __restrict__ edgeG,
                                                const float* __restrict__ posA, const float* __restrict__ posG,
                                                int* __restrict__ gcur, uint2* __restrict__ meta8){
    __shared__ unsigned int lhist[NBUCK];
    __shared__ unsigned int lbase[NBUCK];
    int blk = blockIdx.x;                    // 256 blocks: 0-127 graph A, 128-255 graph G
    int g   = blk >> 7;
    int el0 = (blk & 127) * 4096;
    const int* edge = g ? edgeG : edgeA;
    const float* pos = g ? posG : posA;
    int t = threadIdx.x;
    lhist[t] = 0; lhist[t + 256] = 0;
    __syncthreads();
    unsigned int  mx[16]; float my[16];
    unsigned short rk[16]; unsigned short bb[16];
    #pragma unroll
    for (int j = 0; j < 16; j++){
        int el = el0 + j * 256 + t;
        int src = edge[el], dst = edge[NEDGE + el];
        float dx = pos[src*3+0] - pos[dst*3+0];
        float dy = pos[src*3+1] - pos[dst*3+1];
        float dz = pos[src*3+2] - pos[dst*3+2];
        float d  = sqrtf(fmaf(dx,dx, fmaf(dy,dy, fmaf(dz,dz, 1e-12f))));
        float tp = d * INV_DT;
        int   ti = (int)tp; if (ti > TK - 2) ti = TK - 2;
        float tf = tp - (float)ti;
        int b = dst >> 5;
        bb[j] = (unsigned short)b;
        rk[j] = (unsigned short)atomicAdd(&lhist[b], 1u);
        mx[j] = (unsigned int)src | ((unsigned int)ti << 14) | ((unsigned int)(dst & 31) << 25);
        my[j] = tf;
    }
    __syncthreads();
    lbase[t]       = (unsigned int)atomicAdd(&gcur[g * NBUCK + t],       (int)lhist[t]);
    lbase[t + 256] = (unsigned int)atomicAdd(&gcur[g * NBUCK + t + 256], (int)lhist[t + 256]);
    __syncthreads();
    #pragma unroll
    for (int j = 0; j < 16; j++){
        unsigned int pos_ = lbase[bb[j]] + rk[j];
        meta8[(size_t)g * NEDGE + pos_] = make_uint2(mx[j], __float_as_uint(my[j]));
    }
}

// ---------------- pass 2: per-bucket -> rowptr build + per-dst order scatter (L2-hot)
// metaF: m.x = srcElem(20 = src<<6) | ti<<20(11) ; m.y = half2(1-tf, tf)
__global__ __launch_bounds__(256) void k_place2(const uint2* __restrict__ meta8, const int* __restrict__ bstart,
                                                int* __restrict__ rowptr, uint2* __restrict__ metaF){
    __shared__ int lcnt[32];
    __shared__ int lcur[32];
    int blk = blockIdx.x;                    // 1024: g = blk>>9, bucket = blk&511
    int g = blk >> 9;
    int b = blk & (NBUCK - 1);
    int lo = bstart[g * (NBUCK + 1) + b];
    int hi = bstart[g * (NBUCK + 1) + b + 1];
    int t = threadIdx.x;
    if (t < 32) lcnt[t] = 0;
    __syncthreads();
    for (int idx = lo + t; idx < hi; idx += 256){
        uint2 m = meta8[(size_t)g * NEDGE + idx];
        atomicAdd(&lcnt[(m.x >> 25) & 31u], 1);
    }
    __syncthreads();
    if (t == 0){
        int run = lo;
        int* rp = rowptr + g * (NATOMS + 1) + (b << 5);
        #pragma unroll
        for (int i = 0; i < 32; i++){
            int c = lcnt[i];
            lcur[i] = run;
            rp[i] = run;
            run += c;
        }
        if (b == NBUCK - 1) rowptr[g * (NATOMS + 1) + NATOMS] = hi;
    }
    __syncthreads();
    for (int idx = lo + t; idx < hi; idx += 256){
        uint2 m = meta8[(size_t)g * NEDGE + idx];
        int dl = (int)((m.x >> 25) & 31u);
        int p = atomicAdd(&lcur[dl], 1);
        float tf = __uint_as_float(m.y);
        h2 t2; t2.x = (_Float16)(1.0f - tf); t2.y = (_Float16)tf;
        unsigned int src = m.x & 16383u;
        unsigned int ti  = (m.x >> 14) & 2047u;
        metaF[(size_t)g * NEDGE + p] = make_uint2((src << 6) | (ti << 20),
                                                  __builtin_bit_cast(unsigned int, t2));
    }
}

// ---------------- tabulate W_i(d)*C(d) on TK knots (fp32 scratch)
__global__ __launch_bounds__(256) void k_tables(const float* __restrict__ mw1, const float* __restrict__ mb1,
                                                const float* __restrict__ mw2, const float* __restrict__ mb2,
                                                float* __restrict__ tabf){
    int wv   = blockIdx.x * 4 + (threadIdx.x >> 6);  // < NINT*TK
    int lane = threadIdx.x & 63;
    int i = wv >> 11, k = wv & (TK - 1);
    float d = (float)k * DT;
    const float step  = 10.0f / 49.0f;
    const float coeff = -0.5f / (step * step);
    float u = mb1[(i << 6) + lane];
    #pragma unroll
    for (int gg = 0; gg < NGAUSS; gg++){
        float od = d - (float)gg * step;
        float ea = __expf(coeff * od * od);
        u = fmaf(ea, mw1[((i * NGAUSS + gg) << 6) + lane], u);
    }
    float t = sspf(u);
    float w = mb2[(i << 6) + lane];
    #pragma unroll
    for (int gg = 0; gg < 64; gg++){
        float tg = __shfl(t, gg, 64);
        w = fmaf(tg, mw2[(((i << 6) + gg) << 6) + lane], w);
    }
    float cc = 0.5f * (__cosf(d * 0.31415926535897932f) + 1.0f);
    tabf[((size_t)(i * TK + k) << 6) + lane] = w * cc;
}

// ---------------- pack interleaved half2 table: tab2[k][lane] = (Wk, Wk+1)
__global__ __launch_bounds__(256) void k_pack(const float* __restrict__ tabf, __half2* __restrict__ tab2){
    size_t idx = (size_t)blockIdx.x * 256 + threadIdx.x;   // < NINT*TK*64
    size_t rem = idx & ((size_t)TK * 64 - 1);
    float a = tabf[idx];
    float b = (rem < (size_t)TK * 64 - 64) ? tabf[idx + 64] : a;
    tab2[idx] = __floats2half2_rn(a, b);
}

// ---------------- x = h @ l1w (no bias), 64 nodes per block, fp16 output
__global__ __launch_bounds__(256) void k_lin1(const float* __restrict__ h, const float* __restrict__ w,
                                              __half* __restrict__ x){
    __shared__ float hs[64 * 65];
    __shared__ float ws_[64 * 64];
    int t = threadIdx.x;
    size_t base = (size_t)blockIdx.x * 64;
    #pragma unroll
    for (int j = 0; j < 16; j++){
        int idx = t + j * 256;
        hs[(idx >> 6) * 65 + (idx & 63)] = h[base * 64 + idx];
        ws_[idx] = w[idx];
    }
    __syncthreads();
    int te = t >> 4, tf4 = (t & 15) << 2;
    float acc[4][4];
    #pragma unroll
    for (int j = 0; j < 4; j++){ acc[j][0]=0.f; acc[j][1]=0.f; acc[j][2]=0.f; acc[j][3]=0.f; }
    for (int k = 0; k < 64; k++){
        float4 wv = *(const float4*)&ws_[(k << 6) + tf4];
        #pragma unroll
        for (int j = 0; j < 4; j++){
            float hv = hs[((te << 2) + j) * 65 + k];
            acc[j][0] = fmaf(hv, wv.x, acc[j][0]);
            acc[j][1] = fmaf(hv, wv.y, acc[j][1]);
            acc[j][2] = fmaf(hv, wv.z, acc[j][2]);
            acc[j][3] = fmaf(hv, wv.w, acc[j][3]);
        }
    }
    #pragma unroll
    for (int j = 0; j < 4; j++){
        union { __half2 h2v[2]; float2 f2; } u;
        u.h2v[0] = __floats2half2_rn(acc[j][0], acc[j][1]);
        u.h2v[1] = __floats2half2_rn(acc[j][2], acc[j][3]);
        *(float2*)&x[(base + (te << 2) + j) * 64 + tf4] = u.f2;
    }
}

// ---------------- agg: one wave -> 4 dst atoms, persistent, nt meta/agg, fdot2 lerp
#define PROC(MX, MY, ACC) { \
    int xi_ = (int)((MX) & 0xFFFFFu) + lane; \
    int tb_ = (int)((MX) >> 20) * 64 + lane; \
    h2 tf2_ = __builtin_bit_cast(h2, (MY)); \
    h2 tw_  = __builtin_bit_cast(h2, tabu[tb_]); \
    float w_; \
    _Pragma("clang diagnostic push") \
    w_ = __builtin_amdgcn_fdot2(tw_, tf2_, 0.0f, false); \
    _Pragma("clang diagnostic pop") \
    (ACC) = fmaf(w_, __half2float(xg[xi_]), (ACC)); }

__global__ __launch_bounds__(256) void k_agg(const __half* __restrict__ x, const __half2* __restrict__ tab2,
                                             const uint2* __restrict__ meta, const int* __restrict__ rowptr,
                                             float* __restrict__ agg){
    // XCD partition: (blockIdx&7)<4 -> graph A, else graph G; persistent: 4 dst/wave.
    int b    = blockIdx.x;                 // < 2048
    int xcd  = b & 7;
    int slot = b >> 3;                     // [0,256)
    int g    = xcd >> 2;
    int bi   = (slot << 2) + (xcd & 3);    // [0,1024)
    int wq   = threadIdx.x >> 6;
    int lane = threadIdx.x & 63;
    const int* rp = rowptr + g * (NATOMS + 1);
    const unsigned long long* mg = (const unsigned long long*)(meta + (size_t)g * NEDGE);
    const unsigned int* tabu = (const unsigned int*)tab2;
    const __half* xg = x + ((size_t)(g ? NATOMS : 0) << 6);
    #pragma unroll 1
    for (int it = 0; it < 4; it++){
        int nn = (bi << 4) + (wq << 2) + it;
        int lo = rp[nn], hi = rp[nn + 1];
        float a0 = 0.f, a1 = 0.f, a2 = 0.f, a3 = 0.f;
        int e = lo;
        if (e + 16 <= hi){
            unsigned long long m[16];
            #pragma unroll
            for (int j = 0; j < 16; j++) m[j] = __builtin_nontemporal_load(&mg[e + j]);
            for (; e + 32 <= hi; e += 16){
                unsigned long long n[16];
                #pragma unroll
                for (int j = 0; j < 16; j++) n[j] = __builtin_nontemporal_load(&mg[e + 16 + j]);
                #pragma unroll
                for (int j = 0; j < 16; j += 4){
                    PROC((unsigned int)m[j+0], (unsigned int)(m[j+0] >> 32), a0);
                    PROC((unsigned int)m[j+1], (unsigned int)(m[j+1] >> 32), a1);
                    PROC((unsigned int)m[j+2], (unsigned int)(m[j+2] >> 32), a2);
                    PROC((unsigned int)m[j+3], (unsigned int)(m[j+3] >> 32), a3);
                }
                #pragma unroll
                for (int j = 0; j < 16; j++) m[j] = n[j];
            }
            #pragma unroll
            for (int j = 0; j < 16; j += 4){
                PROC((unsigned int)m[j+0], (unsigned int)(m[j+0] >> 32), a0);
                PROC((unsigned int)m[j+1], (unsigned int)(m[j+1] >> 32), a1);
                PROC((unsigned int)m[j+2], (unsigned int)(m[j+2] >> 32), a2);
                PROC((unsigned int)m[j+3], (unsigned int)(m[j+3] >> 32), a3);
            }
            e += 16;
        }
        for (; e + 4 <= hi; e += 4){
            unsigned long long m0 = __builtin_nontemporal_load(&mg[e]);
            unsigned long long m1 = __builtin_nontemporal_load(&mg[e+1]);
            unsigned long long m2 = __builtin_nontemporal_load(&mg[e+2]);
            unsigned long long m3 = __builtin_nontemporal_load(&mg[e+3]);
            PROC((unsigned int)m0, (unsigned int)(m0 >> 32), a0);
            PROC((unsigned int)m1, (unsigned int)(m1 >> 32), a1);
            PROC((unsigned int)m2, (unsigned int)(m2 >> 32), a2);
            PROC((unsigned int)m3, (unsigned int)(m3 >> 32), a3);
        }
        for (; e < hi; e++){
            unsigned long long m0 = __builtin_nontemporal_load(&mg[e]);
            PROC((unsigned int)m0, (unsigned int)(m0 >> 32), a0);
        }
        __builtin_nontemporal_store((a0 + a1) + (a2 + a3), &agg[((size_t)(g * NATOMS + nn) << 6) + lane]);
    }
}

// ---------------- fused: h += ssp(agg@w2+b2)@w3+b3 ; x = h_new @ w1_next (fp16)
__global__ __launch_bounds__(256) void k_updlin(const float* __restrict__ agg, const float* __restrict__ w2,
                                                const float* __restrict__ b2, const float* __restrict__ w3,
                                                const float* __restrict__ b3, const float* __restrict__ w1n,
                                                float* __restrict__ h, __half* __restrict__ x, int has_x){
    __shared__ float bufA[64 * 65];
    __shared__ float bufT[64 * 65];
    __shared__ float bufW[64 * 64];
    int t = threadIdx.x;
    size_t base = (size_t)blockIdx.x * 64;
    #pragma unroll
    for (int j = 0; j < 16; j++){
        int idx = t + j * 256;
        bufA[(idx >> 6) * 65 + (idx & 63)] = agg[base * 64 + idx];
        bufW[idx] = w2[idx];
    }
    __syncthreads();
    int te = t >> 4, tf4 = (t & 15) << 2;
    float acc[4][4];
    #pragma unroll
    for (int j = 0; j < 4; j++){ acc[j][0]=0.f; acc[j][1]=0.f; acc[j][2]=0.f; acc[j][3]=0.f; }
    for (int k = 0; k < 64; k++){
        float4 wv = *(const float4*)&bufW[(k << 6) + tf4];
        #pragma unroll
        for (int j = 0; j < 4; j++){
            float av = bufA[((te << 2) + j) * 65 + k];
            acc[j][0] = fmaf(av, wv.x, acc[j][0]);
            acc[j][1] = fmaf(av, wv.y, acc[j][1]);
            acc[j][2] = fmaf(av, wv.z, acc[j][2]);
            acc[j][3] = fmaf(av, wv.w, acc[j][3]);
        }
    }
    float4 b2v = *(const float4*)&b2[tf4];
    #pragma unroll
    for (int j = 0; j < 4; j++){
        bufT[((te << 2) + j) * 65 + tf4 + 0] = sspf(acc[j][0] + b2v.x);
        bufT[((te << 2) + j) * 65 + tf4 + 1] = sspf(acc[j][1] + b2v.y);
        bufT[((te << 2) + j) * 65 + tf4 + 2] = sspf(acc[j][2] + b2v.z);
        bufT[((te << 2) + j) * 65 + tf4 + 3] = sspf(acc[j][3] + b2v.w);
    }
    __syncthreads();
    #pragma unroll
    for (int j = 0; j < 16; j++){
        int idx = t + j * 256;
        bufW[idx] = w3[idx];
    }
    __syncthreads();
    #pragma unroll
    for (int j = 0; j < 4; j++){ acc[j][0]=0.f; acc[j][1]=0.f; acc[j][2]=0.f; acc[j][3]=0.f; }
    for (int k = 0; k < 64; k++){
        float4 wv = *(const float4*)&bufW[(k << 6) + tf4];
        #pragma unroll
        for (int j = 0; j < 4; j++){
            float tv = bufT[((te << 2) + j) * 65 + k];
            acc[j][0] = fmaf(tv, wv.x, acc[j][0]);
            acc[j][1] = fmaf(tv, wv.y, acc[j][1]);
            acc[j][2] = fmaf(tv, wv.z, acc[j][2]);
            acc[j][3] = fmaf(tv, wv.w, acc[j][3]);
        }
    }
    float4 b3v = *(const float4*)&b3[tf4];
    #pragma unroll
    for (int j = 0; j < 4; j++){
        size_t o = (base + (te << 2) + j) * 64 + tf4;
        float4 hv = *(float4*)&h[o];
        hv.x += acc[j][0] + b3v.x;
        hv.y += acc[j][1] + b3v.y;
        hv.z += acc[j][2] + b3v.z;
        hv.w += acc[j][3] + b3v.w;
        *(float4*)&h[o] = hv;
        int r = ((te << 2) + j) * 65 + tf4;
        bufA[r + 0] = hv.x; bufA[r + 1] = hv.y; bufA[r + 2] = hv.z; bufA[r + 3] = hv.w;
    }
    if (!has_x) return;
    __syncthreads();
    #pragma unroll
    for (int j = 0; j < 16; j++){
        int idx = t + j * 256;
        bufW[idx] = w1n[idx];
    }
    __syncthreads();
    #pragma unroll
    for (int j = 0; j < 4; j++){ acc[j][0]=0.f; acc[j][1]=0.f; acc[j][2]=0.f; acc[j][3]=0.f; }
    for (int k = 0; k < 64; k++){
        float4 wv = *(const float4*)&bufW[(k << 6) + tf4];
        #pragma unroll
        for (int j = 0; j < 4; j++){
            float hv = bufA[((te << 2) + j) * 65 + k];
            acc[j][0] = fmaf(hv, wv.x, acc[j][0]);
            acc[j][1] = fmaf(hv, wv.y, acc[j][1]);
            acc[j][2] = fmaf(hv, wv.z, acc[j][2]);
            acc[j][3] = fmaf(hv, wv.w, acc[j][3]);
        }
    }
    #pragma unroll
    for (int j = 0; j < 4; j++){
        union { __half2 h2v[2]; float2 f2; } u;
        u.h2v[0] = __floats2half2_rn(acc[j][0], acc[j][1]);
        u.h2v[1] = __floats2half2_rn(acc[j][2], acc[j][3]);
        *(float2*)&x[(base + (te << 2) + j) * 64 + tf4] = u.f2;
    }
}

// ---------------- readout: eout[g][f] = sum_n h[n][f]
__global__ __launch_bounds__(256) void k_readout(const float* __restrict__ h, float* __restrict__ eout){
    int f  = threadIdx.x & 63;
    int wq = threadIdx.x >> 6;
    int nodeBase = blockIdx.x * 256 + wq * 64;
    float acc = 0.f;
    #pragma unroll 4
    for (int j = 0; j < 64; j++) acc += h[(size_t)(nodeBase + j) * 64 + f];
    int g = nodeBase >= NATOMS;
    atomicAdd(&eout[g * 64 + f], acc);
}

// ---------------- head: fc1 -> PReLU -> fc2 -> exp
__global__ __launch_bounds__(64) void k_final(const float* __restrict__ eout, const float* __restrict__ addf,
                                              const float* __restrict__ fc1w, const float* __restrict__ fc1b,
                                              const float* __restrict__ pra, const float* __restrict__ fc2w,
                                              const float* __restrict__ fc2b, float* __restrict__ out){
    int f = threadIdx.x;
    float xv = fc1b[f];
    const float inv = 1.0f / 256.0f;
    for (int k = 0; k < 64; k++)  xv = fmaf(eout[k] * inv,      fc1w[k * 64 + f],        xv);
    for (int k = 0; k < 64; k++)  xv = fmaf(eout[64 + k] * inv, fc1w[(64 + k) * 64 + f], xv);
    xv = fmaf(addf[0], fc1w[128 * 64 + f], xv);
    xv = fmaf(addf[1], fc1w[129 * 64 + f], xv);
    float a = pra[0];
    xv = (xv >= 0.f) ? xv : a * xv;
    float s = xv * fc2w[f];
    #pragma unroll
    for (int m = 32; m >= 1; m >>= 1) s += __shfl_xor(s, m, 64);
    if (f == 0) out[0] = expf(s + fc2b[0]);
}

extern "C" void kernel_launch(void* const* d_in, const int* in_sizes, int n_in,
                              void* d_out, int out_size, void* d_ws, size_t ws_size,
                              hipStream_t stream){
    const int*   zA    = (const int*)  d_in[0];
    const float* posA  = (const float*)d_in[1];
    const int*   edgeA = (const int*)  d_in[3];
    const int*   zG    = (const int*)  d_in[4];
    const float* posG  = (const float*)d_in[5];
    const int*   edgeG = (const int*)  d_in[7];
    const float* addf  = (const float*)d_in[8];
    const float* emb   = (const float*)d_in[9];
    const float* mw1   = (const float*)d_in[10];
    const float* mb1   = (const float*)d_in[11];
    const float* mw2   = (const float*)d_in[12];
    const float* mb2   = (const float*)d_in[13];
    const float* l1w   = (const float*)d_in[14];
    const float* l2w   = (const float*)d_in[15];
    const float* l2b   = (const float*)d_in[16];
    const float* l3w   = (const float*)d_in[17];
    const float* l3b   = (const float*)d_in[18];
    const float* fc1w  = (const float*)d_in[19];
    const float* fc1b  = (const float*)d_in[20];
    const float* pra   = (const float*)d_in[21];
    const float* fc2w  = (const float*)d_in[22];
    const float* fc2b  = (const float*)d_in[23];
    float* out = (float*)d_out;

    // workspace layout (~45 MB)
    char* p = (char*)d_ws;
    auto alloc = [&](size_t bytes)->char*{ char* r = p; p += (bytes + 255) & ~(size_t)255; return r; };
    float*   tabf   = (float*)  alloc((size_t)NINT * TK * 64 * 4);   // 3.1 MB
    __half2* tab2   = (__half2*)alloc((size_t)NINT * TK * 64 * 4);   // 3.1 MB
    uint2*   meta8  = (uint2*)  alloc((size_t)2 * NEDGE * 8);        // 8.4 MB
    uint2*   metaF  = (uint2*)  alloc((size_t)2 * NEDGE * 8);        // 8.4 MB
    int*     rowptr = (int*)    alloc((size_t)2 * (NATOMS + 1) * 4);
    int*     gcur   = (int*)    alloc((size_t)2 * NBUCK * 4);
    int*     bhist  = (int*)    alloc((size_t)2 * NBUCK * 4);
    int*     bstart = (int*)    alloc((size_t)2 * (NBUCK + 1) * 4);
    float*   h      = (float*)  alloc((size_t)2 * NATOMS * 64 * 4);  // 8.4 MB
    __half*  x      = (__half*) alloc((size_t)2 * NATOMS * 64 * 2);  // 4.2 MB
    float*   agg    = (float*)  alloc((size_t)2 * NATOMS * 64 * 4);  // 8.4 MB
    float*   eout   = (float*)  alloc(128 * 4);

    hipMemsetAsync(bhist, 0, (size_t)2 * NBUCK * 4, stream);
    hipMemsetAsync(eout, 0, 128 * 4, stream);

    k_embed <<<(2 * NATOMS * 64) / 256, 256, 0, stream>>>(zA, zG, emb, h);
    k_bhist <<<256, 256, 0, stream>>>(edgeA, edgeG, bhist);
    k_bscan <<<2, 512, 0, stream>>>(bhist, bstart, gcur);
    k_place1<<<256,  256, 0, stream>>>(edgeA, edgeG, posA, posG, gcur, meta8);
    k_place2<<<1024, 256, 0, stream>>>(meta8, bstart, rowptr, metaF);
    k_tables<<<(NINT * TK) / 4,        256, 0, stream>>>(mw1, mb1, mw2, mb2, tabf);
    k_pack  <<<(NINT * TK * 64) / 256, 256, 0, stream>>>(tabf, tab2);

    k_lin1<<<(2 * NATOMS) / 64, 256, 0, stream>>>(h, l1w, x);
    for (int i = 0; i < NINT; i++){
        k_agg   <<<2048, 256, 0, stream>>>(x, tab2 + (size_t)i * TK * 64, metaF, rowptr, agg);
        int has_x = (i < NINT - 1);
        const float* w1n = has_x ? (l1w + (i + 1) * 4096) : l1w;
        k_updlin<<<(2 * NATOMS) / 64, 256, 0, stream>>>(agg, l2w + i * 4096, l2b + i * 64,
                                                        l3w + i * 4096, l3b + i * 64, w1n, h, x, has_x);
    }

    k_readout<<<(2 * NATOMS) / 256, 256, 0, stream>>>(h, eout);
    k_final  <<<1, 64, 0, stream>>>(eout, addf, fc1w, fc1b, pra, fc2w, fc2b, out);
}

// Round 7
// 590.147 us; speedup vs baseline: 1.0661x; 1.0661x over previous
//
#include <hip/hip_runtime.h>
#include <hip/hip_bf16.h>
#include <hip/hip_fp16.h>
#include <math.h>

#define NATOMS 16384
#define NEDGE  524288
#define NINT   6
#define NGAUSS 50
#define TK     2048
#define INV_DT 128.0f    // knots at d = k/128, range [0,16)
#define DT     (1.0f/128.0f)
#define LOG2F_ 0.69314718055994530942f
#define NBUCK  512       // per graph, 32 dst atoms each

typedef _Float16 h2   __attribute__((ext_vector_type(2)));
typedef _Float16 f16x8 __attribute__((ext_vector_type(8)));
typedef float    f32x4 __attribute__((ext_vector_type(4)));

__device__ __forceinline__ float sspf(float v){
    return fmaxf(v, 0.f) + log1pf(__expf(-fabsf(v))) - LOG2F_;
}

// ---------------- h = emb[z]  (rows 0..N-1 = A, N..2N-1 = G)
__global__ __launch_bounds__(256) void k_embed(const int* __restrict__ zA, const int* __restrict__ zG,
                                               const float* __restrict__ emb, float* __restrict__ h){
    int idx = blockIdx.x * 256 + threadIdx.x;        // < 2*NATOMS*64
    int n = idx >> 6, f = idx & 63;
    int z = (n < NATOMS) ? zA[n] : zG[n - NATOMS];
    h[idx] = emb[(z << 6) + f];
}

// ---------------- bucket histogram (LDS-privatized, coalesced global adds)
__global__ __launch_bounds__(256) void k_bhist(const int* __restrict__ edgeA, const int* __restrict__ edgeG,
                                               int* __restrict__ bhist){
    __shared__ int lh[NBUCK];
    int blk = blockIdx.x;                    // 256: 0-127 graph A, 128-255 graph G
    int g   = blk >> 7;
    int e0  = (blk & 127) * 4096;
    const int* dst = (g ? edgeG : edgeA) + NEDGE;
    int t = threadIdx.x;
    lh[t] = 0; lh[t + 256] = 0;
    __syncthreads();
    #pragma unroll
    for (int j = 0; j < 16; j++){
        int d = dst[e0 + j * 256 + t];
        atomicAdd(&lh[d >> 5], 1);
    }
    __syncthreads();
    atomicAdd(&bhist[g * NBUCK + t],       lh[t]);
    atomicAdd(&bhist[g * NBUCK + 256 + t], lh[t + 256]);
}

// ---------------- bucket exclusive scan -> bstart (513/graph) + gcur init
__global__ __launch_bounds__(512) void k_bscan(const int* __restrict__ bhist, int* __restrict__ bstart,
                                               int* __restrict__ gcur){
    int g = blockIdx.x;
    __shared__ int s[NBUCK];
    int t = threadIdx.x;
    int v = bhist[g * NBUCK + t];
    s[t] = v;
    __syncthreads();
    for (int off = 1; off < NBUCK; off <<= 1){
        int a = (t >= off) ? s[t - off] : 0;
        __syncthreads();
        s[t] += a;
        __syncthreads();
    }
    int ex = s[t] - v;
    bstart[g * (NBUCK + 1) + t] = ex;
    gcur[g * NBUCK + t] = ex;
    if (t == NBUCK - 1) bstart[g * (NBUCK + 1) + NBUCK] = s[NBUCK - 1];
}

// ---------------- pass 1: bucket-binned placement (coherent writes)
__global__ __launch_bounds__(256) void k_place1(const int* __restrict__ edgeA, const int* __restrict__ edgeG,
                                                const float* __restrict__ posA, const float* __restrict__ posG,
                                                int* __restrict__ gcur, uint2* __restrict__ meta8){
    __shared__ unsigned int lhist[NBUCK];
    __shared__ unsigned int lbase[NBUCK];
    int blk = blockIdx.x;
    int g   = blk >> 7;
    int el0 = (blk & 127) * 4096;
    const int* edge = g ? edgeG : edgeA;
    const float* pos = g ? posG : posA;
    int t = threadIdx.x;
    lhist[t] = 0; lhist[t + 256] = 0;
    __syncthreads();
    unsigned int  mx[16]; float my[16];
    unsigned short rk[16]; unsigned short bb[16];
    #pragma unroll
    for (int j = 0; j < 16; j++){
        int el = el0 + j * 256 + t;
        int src = edge[el], dst = edge[NEDGE + el];
        float dx = pos[src*3+0] - pos[dst*3+0];
        float dy = pos[src*3+1] - pos[dst*3+1];
        float dz = pos[src*3+2] - pos[dst*3+2];
        float d  = sqrtf(fmaf(dx,dx, fmaf(dy,dy, fmaf(dz,dz, 1e-12f))));
        float tp = d * INV_DT;
        int   ti = (int)tp; if (ti > TK - 2) ti = TK - 2;
        float tf = tp - (float)ti;
        int b = dst >> 5;
        bb[j] = (unsigned short)b;
        rk[j] = (unsigned short)atomicAdd(&lhist[b], 1u);
        mx[j] = (unsigned int)src | ((unsigned int)ti << 14) | ((unsigned int)(dst & 31) << 25);
        my[j] = tf;
    }
    __syncthreads();
    lbase[t]       = (unsigned int)atomicAdd(&gcur[g * NBUCK + t],       (int)lhist[t]);
    lbase[t + 256] = (unsigned int)atomicAdd(&gcur[g * NBUCK + t + 256], (int)lhist[t + 256]);
    __syncthreads();
    #pragma unroll
    for (int j = 0; j < 16; j++){
        unsigned int pos_ = lbase[bb[j]] + rk[j];
        meta8[(size_t)g * NEDGE + pos_] = make_uint2(mx[j], __float_as_uint(my[j]));
    }
}

// ---------------- pass 2: per-bucket rowptr build + per-dst scatter (L2-hot)
// metaF: m.x = srcElem(20 = src<<6) | ti<<20(11) ; m.y = half2(1-tf, tf)
__global__ __launch_bounds__(256) void k_place2(const uint2* __restrict__ meta8, const int* __restrict__ bstart,
                                                int* __restrict__ rowptr, uint2* __restrict__ metaF){
    __shared__ int lcnt[32];
    __shared__ int lcur[32];
    int blk = blockIdx.x;
    int g = blk >> 9;
    int b = blk & (NBUCK - 1);
    int lo = bstart[g * (NBUCK + 1) + b];
    int hi = bstart[g * (NBUCK + 1) + b + 1];
    int t = threadIdx.x;
    if (t < 32) lcnt[t] = 0;
    __syncthreads();
    for (int idx = lo + t; idx < hi; idx += 256){
        uint2 m = meta8[(size_t)g * NEDGE + idx];
        atomicAdd(&lcnt[(m.x >> 25) & 31u], 1);
    }
    __syncthreads();
    if (t == 0){
        int run = lo;
        int* rp = rowptr + g * (NATOMS + 1) + (b << 5);
        #pragma unroll
        for (int i = 0; i < 32; i++){
            int c = lcnt[i];
            lcur[i] = run;
            rp[i] = run;
            run += c;
        }
        if (b == NBUCK - 1) rowptr[g * (NATOMS + 1) + NATOMS] = hi;
    }
    __syncthreads();
    for (int idx = lo + t; idx < hi; idx += 256){
        uint2 m = meta8[(size_t)g * NEDGE + idx];
        int dl = (int)((m.x >> 25) & 31u);
        int p = atomicAdd(&lcur[dl], 1);
        float tf = __uint_as_float(m.y);
        h2 t2; t2.x = (_Float16)(1.0f - tf); t2.y = (_Float16)tf;
        unsigned int src = m.x & 16383u;
        unsigned int ti  = (m.x >> 14) & 2047u;
        metaF[(size_t)g * NEDGE + p] = make_uint2((src << 6) | (ti << 20),
                                                  __builtin_bit_cast(unsigned int, t2));
    }
}

// ---------------- tabulate W_i(d)*C(d) on TK knots (fp32 scratch)
__global__ __launch_bounds__(256) void k_tables(const float* __restrict__ mw1, const float* __restrict__ mb1,
                                                const float* __restrict__ mw2, const float* __restrict__ mb2,
                                                float* __restrict__ tabf){
    int wv   = blockIdx.x * 4 + (threadIdx.x >> 6);
    int lane = threadIdx.x & 63;
    int i = wv >> 11, k = wv & (TK - 1);
    float d = (float)k * DT;
    const float step  = 10.0f / 49.0f;
    const float coeff = -0.5f / (step * step);
    float u = mb1[(i << 6) + lane];
    #pragma unroll
    for (int gg = 0; gg < NGAUSS; gg++){
        float od = d - (float)gg * step;
        float ea = __expf(coeff * od * od);
        u = fmaf(ea, mw1[((i * NGAUSS + gg) << 6) + lane], u);
    }
    float t = sspf(u);
    float w = mb2[(i << 6) + lane];
    #pragma unroll
    for (int gg = 0; gg < 64; gg++){
        float tg = __shfl(t, gg, 64);
        w = fmaf(tg, mw2[(((i << 6) + gg) << 6) + lane], w);
    }
    float cc = 0.5f * (__cosf(d * 0.31415926535897932f) + 1.0f);
    tabf[((size_t)(i * TK + k) << 6) + lane] = w * cc;
}

// ---------------- pack interleaved half2 table: tab2[k][lane] = (Wk, Wk+1)
__global__ __launch_bounds__(256) void k_pack(const float* __restrict__ tabf, __half2* __restrict__ tab2){
    size_t idx = (size_t)blockIdx.x * 256 + threadIdx.x;
    size_t rem = idx & ((size_t)TK * 64 - 1);
    float a = tabf[idx];
    float b = (rem < (size_t)TK * 64 - 64) ? tabf[idx + 64] : a;
    tab2[idx] = __floats2half2_rn(a, b);
}

// ---------------- agg: one wave per dst atom, XCD-partitioned, fp16 out, fdot2 lerp
#define PROC(MX, MY, ACC) { \
    int xi_ = (int)((MX) & 0xFFFFFu) + lane; \
    int tb_ = (int)((MX) >> 20) * 64 + lane; \
    h2 tf2_ = __builtin_bit_cast(h2, (MY)); \
    h2 tw_  = __builtin_bit_cast(h2, tabu[tb_]); \
    float w_ = __builtin_amdgcn_fdot2(tw_, tf2_, 0.0f, false); \
    (ACC) = fmaf(w_, __half2float(xg[xi_]), (ACC)); }

__global__ __launch_bounds__(256) void k_agg(const __half* __restrict__ x, const __half2* __restrict__ tab2,
                                             const uint2* __restrict__ meta, const int* __restrict__ rowptr,
                                             __half* __restrict__ agg){
    // XCD partition: (blockIdx&7)<4 -> graph A, else graph G; 1 dst per wave.
    int b    = blockIdx.x;                 // < 8192
    int xcd  = b & 7;
    int slot = b >> 3;
    int g    = xcd >> 2;
    int bi   = (slot << 2) + (xcd & 3);    // [0,4096)
    int wq   = threadIdx.x >> 6;
    int lane = threadIdx.x & 63;
    int nn   = (bi << 2) + wq;             // dst atom within graph
    const int* rp = rowptr + g * (NATOMS + 1);
    int lo = rp[nn], hi = rp[nn + 1];
    const unsigned long long* mg = (const unsigned long long*)(meta + (size_t)g * NEDGE);
    const unsigned int* tabu = (const unsigned int*)tab2;
    const __half* xg = x + ((size_t)(g ? NATOMS : 0) << 6);
    float a0 = 0.f, a1 = 0.f, a2 = 0.f, a3 = 0.f;
    int e = lo;
    if (e + 16 <= hi){
        unsigned long long m[16];
        #pragma unroll
        for (int j = 0; j < 16; j++) m[j] = __builtin_nontemporal_load(&mg[e + j]);
        for (; e + 32 <= hi; e += 16){
            unsigned long long n[16];
            #pragma unroll
            for (int j = 0; j < 16; j++) n[j] = __builtin_nontemporal_load(&mg[e + 16 + j]);
            #pragma unroll
            for (int j = 0; j < 16; j += 4){
                PROC((unsigned int)m[j+0], (unsigned int)(m[j+0] >> 32), a0);
                PROC((unsigned int)m[j+1], (unsigned int)(m[j+1] >> 32), a1);
                PROC((unsigned int)m[j+2], (unsigned int)(m[j+2] >> 32), a2);
                PROC((unsigned int)m[j+3], (unsigned int)(m[j+3] >> 32), a3);
            }
            #pragma unroll
            for (int j = 0; j < 16; j++) m[j] = n[j];
        }
        #pragma unroll
        for (int j = 0; j < 16; j += 4){
            PROC((unsigned int)m[j+0], (unsigned int)(m[j+0] >> 32), a0);
            PROC((unsigned int)m[j+1], (unsigned int)(m[j+1] >> 32), a1);
            PROC((unsigned int)m[j+2], (unsigned int)(m[j+2] >> 32), a2);
            PROC((unsigned int)m[j+3], (unsigned int)(m[j+3] >> 32), a3);
        }
        e += 16;
    }
    for (; e + 4 <= hi; e += 4){
        unsigned long long m0 = __builtin_nontemporal_load(&mg[e]);
        unsigned long long m1 = __builtin_nontemporal_load(&mg[e+1]);
        unsigned long long m2 = __builtin_nontemporal_load(&mg[e+2]);
        unsigned long long m3 = __builtin_nontemporal_load(&mg[e+3]);
        PROC((unsigned int)m0, (unsigned int)(m0 >> 32), a0);
        PROC((unsigned int)m1, (unsigned int)(m1 >> 32), a1);
        PROC((unsigned int)m2, (unsigned int)(m2 >> 32), a2);
        PROC((unsigned int)m3, (unsigned int)(m3 >> 32), a3);
    }
    for (; e < hi; e++){
        unsigned long long m0 = __builtin_nontemporal_load(&mg[e]);
        PROC((unsigned int)m0, (unsigned int)(m0 >> 32), a0);
    }
    agg[((size_t)(g * NATOMS + nn) << 6) + lane] = __float2half((a0 + a1) + (a2 + a3));
}

// ---------------- MFMA node GEMMs. mode 1: h += ssp(agg@w2+b2)@w3+b3; x = h_new@w1n
//                  mode 0: x = h @ w1n  (lin1)
// 64 nodes per block, 4 waves; A-tile + transposed-W fp16 in LDS (row pad +8).
__global__ __launch_bounds__(256) void k_updlin(const __half* __restrict__ agg, const float* __restrict__ w2,
                                                const float* __restrict__ b2, const float* __restrict__ w3,
                                                const float* __restrict__ b3, const float* __restrict__ w1n,
                                                float* __restrict__ h, __half* __restrict__ x,
                                                int mode, int has_x){
    __shared__ _Float16 A_lds[64 * 72];
    __shared__ _Float16 W_lds[64 * 72];
    int t = threadIdx.x;
    int w = t >> 6, lane = t & 63;
    int m = lane & 15, kg = lane >> 4;
    size_t base = (size_t)blockIdx.x * 64;

    // stage A
    if (mode == 1){
        const unsigned int* ag = (const unsigned int*)(agg + base * 64);
        #pragma unroll
        for (int j = 0; j < 8; j++){
            int idx = j * 256 + t;              // < 2048 u32
            int row = idx >> 5, cu = idx & 31;
            *(unsigned int*)&A_lds[row * 72 + cu * 2] = ag[idx];
        }
    } else {
        #pragma unroll
        for (int j = 0; j < 16; j++){
            int idx = j * 256 + t;              // < 4096
            A_lds[(idx >> 6) * 72 + (idx & 63)] = (_Float16)h[base * 64 + idx];
        }
    }
    // stage first weight (transposed)
    const float* wfirst = (mode == 1) ? w2 : w1n;
    #pragma unroll
    for (int j = 0; j < 16; j++){
        int idx = j * 256 + t;
        W_lds[(idx & 63) * 72 + (idx >> 6)] = (_Float16)wfirst[idx];
    }
    __syncthreads();

    int arow = (w << 4) + m;                    // A-frag row for this lane
    f32x4 acc[4];

#define GEMM_4CB() { \
    acc[0] = (f32x4)0.f; acc[1] = (f32x4)0.f; acc[2] = (f32x4)0.f; acc[3] = (f32x4)0.f; \
    _Pragma("unroll") \
    for (int kh = 0; kh < 2; kh++){ \
        f16x8 av = *(const f16x8*)&A_lds[arow * 72 + kh * 32 + kg * 8]; \
        _Pragma("unroll") \
        for (int cb = 0; cb < 4; cb++){ \
            f16x8 bv = *(const f16x8*)&W_lds[((cb << 4) + m) * 72 + kh * 32 + kg * 8]; \
            acc[cb] = __builtin_amdgcn_mfma_f32_16x16x32_f16(av, bv, acc[cb], 0, 0, 0); \
        } \
    } }

    if (mode == 0){
        GEMM_4CB();
        #pragma unroll
        for (int cb = 0; cb < 4; cb++){
            int col = (cb << 4) + m;
            #pragma unroll
            for (int v = 0; v < 4; v++){
                int row = (w << 4) + (kg << 2) + v;
                x[(base + row) * 64 + col] = __float2half(acc[cb][v]);
            }
        }
        return;
    }

    // GEMM1: t = ssp(agg @ w2 + b2)  -> A_lds (own rows)
    GEMM_4CB();
    #pragma unroll
    for (int cb = 0; cb < 4; cb++){
        int col = (cb << 4) + m;
        float bv = b2[col];
        #pragma unroll
        for (int v = 0; v < 4; v++){
            int row = (w << 4) + (kg << 2) + v;
            A_lds[row * 72 + col] = (_Float16)sspf(acc[cb][v] + bv);
        }
    }
    __syncthreads();
    #pragma unroll
    for (int j = 0; j < 16; j++){
        int idx = j * 256 + t;
        W_lds[(idx & 63) * 72 + (idx >> 6)] = (_Float16)w3[idx];
    }
    __syncthreads();

    // GEMM2: h_new = t @ w3 + b3 + h  (global h update; h_new -> A_lds)
    GEMM_4CB();
    #pragma unroll
    for (int cb = 0; cb < 4; cb++){
        int col = (cb << 4) + m;
        float bv = b3[col];
        #pragma unroll
        for (int v = 0; v < 4; v++){
            int row = (w << 4) + (kg << 2) + v;
            size_t o = (base + row) * 64 + col;
            float hv = h[o] + acc[cb][v] + bv;
            h[o] = hv;
            A_lds[row * 72 + col] = (_Float16)hv;
        }
    }
    if (!has_x) return;
    __syncthreads();
    #pragma unroll
    for (int j = 0; j < 16; j++){
        int idx = j * 256 + t;
        W_lds[(idx & 63) * 72 + (idx >> 6)] = (_Float16)w1n[idx];
    }
    __syncthreads();

    // GEMM3: x = h_new @ w1_next  (fp16 out)
    GEMM_4CB();
    #pragma unroll
    for (int cb = 0; cb < 4; cb++){
        int col = (cb << 4) + m;
        #pragma unroll
        for (int v = 0; v < 4; v++){
            int row = (w << 4) + (kg << 2) + v;
            x[(base + row) * 64 + col] = __float2half(acc[cb][v]);
        }
    }
#undef GEMM_4CB
}

// ---------------- readout: eout[g][f] = sum_n h[n][f]
__global__ __launch_bounds__(256) void k_readout(const float* __restrict__ h, float* __restrict__ eout){
    int f  = threadIdx.x & 63;
    int wq = threadIdx.x >> 6;
    int nodeBase = blockIdx.x * 256 + wq * 64;
    float acc = 0.f;
    #pragma unroll 4
    for (int j = 0; j < 64; j++) acc += h[(size_t)(nodeBase + j) * 64 + f];
    int g = nodeBase >= NATOMS;
    atomicAdd(&eout[g * 64 + f], acc);
}

// ---------------- head: fc1 -> PReLU -> fc2 -> exp
__global__ __launch_bounds__(64) void k_final(const float* __restrict__ eout, const float* __restrict__ addf,
                                              const float* __restrict__ fc1w, const float* __restrict__ fc1b,
                                              const float* __restrict__ pra, const float* __restrict__ fc2w,
                                              const float* __restrict__ fc2b, float* __restrict__ out){
    int f = threadIdx.x;
    float xv = fc1b[f];
    const float inv = 1.0f / 256.0f;
    for (int k = 0; k < 64; k++)  xv = fmaf(eout[k] * inv,      fc1w[k * 64 + f],        xv);
    for (int k = 0; k < 64; k++)  xv = fmaf(eout[64 + k] * inv, fc1w[(64 + k) * 64 + f], xv);
    xv = fmaf(addf[0], fc1w[128 * 64 + f], xv);
    xv = fmaf(addf[1], fc1w[129 * 64 + f], xv);
    float a = pra[0];
    xv = (xv >= 0.f) ? xv : a * xv;
    float s = xv * fc2w[f];
    #pragma unroll
    for (int m = 32; m >= 1; m >>= 1) s += __shfl_xor(s, m, 64);
    if (f == 0) out[0] = expf(s + fc2b[0]);
}

extern "C" void kernel_launch(void* const* d_in, const int* in_sizes, int n_in,
                              void* d_out, int out_size, void* d_ws, size_t ws_size,
                              hipStream_t stream){
    const int*   zA    = (const int*)  d_in[0];
    const float* posA  = (const float*)d_in[1];
    const int*   edgeA = (const int*)  d_in[3];
    const int*   zG    = (const int*)  d_in[4];
    const float* posG  = (const float*)d_in[5];
    const int*   edgeG = (const int*)  d_in[7];
    const float* addf  = (const float*)d_in[8];
    const float* emb   = (const float*)d_in[9];
    const float* mw1   = (const float*)d_in[10];
    const float* mb1   = (const float*)d_in[11];
    const float* mw2   = (const float*)d_in[12];
    const float* mb2   = (const float*)d_in[13];
    const float* l1w   = (const float*)d_in[14];
    const float* l2w   = (const float*)d_in[15];
    const float* l2b   = (const float*)d_in[16];
    const float* l3w   = (const float*)d_in[17];
    const float* l3b   = (const float*)d_in[18];
    const float* fc1w  = (const float*)d_in[19];
    const float* fc1b  = (const float*)d_in[20];
    const float* pra   = (const float*)d_in[21];
    const float* fc2w  = (const float*)d_in[22];
    const float* fc2b  = (const float*)d_in[23];
    float* out = (float*)d_out;

    // workspace layout (~42 MB)
    char* p = (char*)d_ws;
    auto alloc = [&](size_t bytes)->char*{ char* r = p; p += (bytes + 255) & ~(size_t)255; return r; };
    float*   tabf   = (float*)  alloc((size_t)NINT * TK * 64 * 4);   // 3.1 MB
    __half2* tab2   = (__half2*)alloc((size_t)NINT * TK * 64 * 4);   // 3.1 MB
    uint2*   meta8  = (uint2*)  alloc((size_t)2 * NEDGE * 8);        // 8.4 MB
    uint2*   metaF  = (uint2*)  alloc((size_t)2 * NEDGE * 8);        // 8.4 MB
    int*     rowptr = (int*)    alloc((size_t)2 * (NATOMS + 1) * 4);
    int*     gcur   = (int*)    alloc((size_t)2 * NBUCK * 4);
    int*     bhist  = (int*)    alloc((size_t)2 * NBUCK * 4);
    int*     bstart = (int*)    alloc((size_t)2 * (NBUCK + 1) * 4);
    float*   h      = (float*)  alloc((size_t)2 * NATOMS * 64 * 4);  // 8.4 MB
    __half*  x      = (__half*) alloc((size_t)2 * NATOMS * 64 * 2);  // 4.2 MB
    __half*  agg    = (__half*) alloc((size_t)2 * NATOMS * 64 * 2);  // 4.2 MB
    float*   eout   = (float*)  alloc(128 * 4);

    hipMemsetAsync(bhist, 0, (size_t)2 * NBUCK * 4, stream);
    hipMemsetAsync(eout, 0, 128 * 4, stream);

    k_embed <<<(2 * NATOMS * 64) / 256, 256, 0, stream>>>(zA, zG, emb, h);
    k_bhist <<<256, 256, 0, stream>>>(edgeA, edgeG, bhist);
    k_bscan <<<2, 512, 0, stream>>>(bhist, bstart, gcur);
    k_place1<<<256,  256, 0, stream>>>(edgeA, edgeG, posA, posG, gcur, meta8);
    k_place2<<<1024, 256, 0, stream>>>(meta8, bstart, rowptr, metaF);
    k_tables<<<(NINT * TK) / 4,        256, 0, stream>>>(mw1, mb1, mw2, mb2, tabf);
    k_pack  <<<(NINT * TK * 64) / 256, 256, 0, stream>>>(tabf, tab2);

    // lin1 (mode 0)
    k_updlin<<<(2 * NATOMS) / 64, 256, 0, stream>>>(agg, l2w, l2b, l3w, l3b, l1w, h, x, 0, 1);
    for (int i = 0; i < NINT; i++){
        k_agg<<<(2 * NATOMS) / 4, 256, 0, stream>>>(x, tab2 + (size_t)i * TK * 64, metaF, rowptr, agg);
        int has_x = (i < NINT - 1);
        const float* w1n = has_x ? (l1w + (i + 1) * 4096) : l1w;
        k_updlin<<<(2 * NATOMS) / 64, 256, 0, stream>>>(agg, l2w + i * 4096, l2b + i * 64,
                                                        l3w + i * 4096, l3b + i * 64, w1n, h, x, 1, has_x);
    }

    k_readout<<<(2 * NATOMS) / 256, 256, 0, stream>>>(h, eout);
    k_final  <<<1, 64, 0, stream>>>(eout, addf, fc1w, fc1b, pra, fc2w, fc2b, out);
}

// Round 8
// 441.101 us; speedup vs baseline: 1.4263x; 1.3379x over previous
//
#include <hip/hip_runtime.h>
#include <hip/hip_bf16.h>
#include <hip/hip_fp16.h>
#include <math.h>

#define NATOMS 16384
#define NEDGE  524288
#define NINT   6
#define NGAUSS 50
#define TK     2048
#define INV_DT 128.0f    // knots at d = k/128, range [0,16)
#define DT     (1.0f/128.0f)
#define LOG2F_ 0.69314718055994530942f
#define NBUCK  512       // per graph, 32 dst atoms each

typedef _Float16 h2    __attribute__((ext_vector_type(2)));
typedef _Float16 f16x8 __attribute__((ext_vector_type(8)));
typedef float    f32x4 __attribute__((ext_vector_type(4)));

__device__ __forceinline__ float sspf(float v){
    return fmaxf(v, 0.f) + log1pf(__expf(-fabsf(v))) - LOG2F_;
}

// ---------------- h = emb[z]  (rows 0..N-1 = A, N..2N-1 = G)
__global__ __launch_bounds__(256) void k_embed(const int* __restrict__ zA, const int* __restrict__ zG,
                                               const float* __restrict__ emb, float* __restrict__ h){
    int idx = blockIdx.x * 256 + threadIdx.x;        // < 2*NATOMS*64
    int n = idx >> 6, f = idx & 63;
    int z = (n < NATOMS) ? zA[n] : zG[n - NATOMS];
    h[idx] = emb[(z << 6) + f];
}

// ---------------- bucket histogram (LDS-privatized, coalesced global adds)
__global__ __launch_bounds__(256) void k_bhist(const int* __restrict__ edgeA, const int* __restrict__ edgeG,
                                               int* __restrict__ bhist){
    __shared__ int lh[NBUCK];
    int blk = blockIdx.x;                    // 256: 0-127 graph A, 128-255 graph G
    int g   = blk >> 7;
    int e0  = (blk & 127) * 4096;
    const int* dst = (g ? edgeG : edgeA) + NEDGE;
    int t = threadIdx.x;
    lh[t] = 0; lh[t + 256] = 0;
    __syncthreads();
    #pragma unroll
    for (int j = 0; j < 16; j++){
        int d = dst[e0 + j * 256 + t];
        atomicAdd(&lh[d >> 5], 1);
    }
    __syncthreads();
    atomicAdd(&bhist[g * NBUCK + t],       lh[t]);
    atomicAdd(&bhist[g * NBUCK + 256 + t], lh[t + 256]);
}

// ---------------- bucket exclusive scan -> bstart (513/graph) + gcur init
__global__ __launch_bounds__(512) void k_bscan(const int* __restrict__ bhist, int* __restrict__ bstart,
                                               int* __restrict__ gcur){
    int g = blockIdx.x;
    __shared__ int s[NBUCK];
    int t = threadIdx.x;
    int v = bhist[g * NBUCK + t];
    s[t] = v;
    __syncthreads();
    for (int off = 1; off < NBUCK; off <<= 1){
        int a = (t >= off) ? s[t - off] : 0;
        __syncthreads();
        s[t] += a;
        __syncthreads();
    }
    int ex = s[t] - v;
    bstart[g * (NBUCK + 1) + t] = ex;
    gcur[g * NBUCK + t] = ex;
    if (t == NBUCK - 1) bstart[g * (NBUCK + 1) + NBUCK] = s[NBUCK - 1];
}

// ---------------- pass 1: bucket-binned placement (coherent writes)
__global__ __launch_bounds__(256) void k_place1(const int* __restrict__ edgeA, const int* __restrict__ edgeG,
                                                const float* __restrict__ posA, const float* __restrict__ posG,
                                                int* __restrict__ gcur, uint2* __restrict__ meta8){
    __shared__ unsigned int lhist[NBUCK];
    __shared__ unsigned int lbase[NBUCK];
    int blk = blockIdx.x;
    int g   = blk >> 7;
    int el0 = (blk & 127) * 4096;
    const int* edge = g ? edgeG : edgeA;
    const float* pos = g ? posG : posA;
    int t = threadIdx.x;
    lhist[t] = 0; lhist[t + 256] = 0;
    __syncthreads();
    unsigned int  mx[16]; float my[16];
    unsigned short rk[16]; unsigned short bb[16];
    #pragma unroll
    for (int j = 0; j < 16; j++){
        int el = el0 + j * 256 + t;
        int src = edge[el], dst = edge[NEDGE + el];
        float dx = pos[src*3+0] - pos[dst*3+0];
        float dy = pos[src*3+1] - pos[dst*3+1];
        float dz = pos[src*3+2] - pos[dst*3+2];
        float d  = sqrtf(fmaf(dx,dx, fmaf(dy,dy, fmaf(dz,dz, 1e-12f))));
        float tp = d * INV_DT;
        int   ti = (int)tp; if (ti > TK - 2) ti = TK - 2;
        float tf = tp - (float)ti;
        int b = dst >> 5;
        bb[j] = (unsigned short)b;
        rk[j] = (unsigned short)atomicAdd(&lhist[b], 1u);
        mx[j] = (unsigned int)src | ((unsigned int)ti << 14) | ((unsigned int)(dst & 31) << 25);
        my[j] = tf;
    }
    __syncthreads();
    lbase[t]       = (unsigned int)atomicAdd(&gcur[g * NBUCK + t],       (int)lhist[t]);
    lbase[t + 256] = (unsigned int)atomicAdd(&gcur[g * NBUCK + t + 256], (int)lhist[t + 256]);
    __syncthreads();
    #pragma unroll
    for (int j = 0; j < 16; j++){
        unsigned int pos_ = lbase[bb[j]] + rk[j];
        meta8[(size_t)g * NEDGE + pos_] = make_uint2(mx[j], __float_as_uint(my[j]));
    }
}

// ---------------- pass 2: per-bucket rowptr build + per-dst scatter (L2-hot)
// metaF: m.x = srcElem(20 = src<<6) | ti<<20(11) ; m.y = half2(1-tf, tf)
__global__ __launch_bounds__(256) void k_place2(const uint2* __restrict__ meta8, const int* __restrict__ bstart,
                                                int* __restrict__ rowptr, uint2* __restrict__ metaF){
    __shared__ int lcnt[32];
    __shared__ int lcur[32];
    int blk = blockIdx.x;
    int g = blk >> 9;
    int b = blk & (NBUCK - 1);
    int lo = bstart[g * (NBUCK + 1) + b];
    int hi = bstart[g * (NBUCK + 1) + b + 1];
    int t = threadIdx.x;
    if (t < 32) lcnt[t] = 0;
    __syncthreads();
    for (int idx = lo + t; idx < hi; idx += 256){
        uint2 m = meta8[(size_t)g * NEDGE + idx];
        atomicAdd(&lcnt[(m.x >> 25) & 31u], 1);
    }
    __syncthreads();
    if (t == 0){
        int run = lo;
        int* rp = rowptr + g * (NATOMS + 1) + (b << 5);
        #pragma unroll
        for (int i = 0; i < 32; i++){
            int c = lcnt[i];
            lcur[i] = run;
            rp[i] = run;
            run += c;
        }
        if (b == NBUCK - 1) rowptr[g * (NATOMS + 1) + NATOMS] = hi;
    }
    __syncthreads();
    for (int idx = lo + t; idx < hi; idx += 256){
        uint2 m = meta8[(size_t)g * NEDGE + idx];
        int dl = (int)((m.x >> 25) & 31u);
        int p = atomicAdd(&lcur[dl], 1);
        float tf = __uint_as_float(m.y);
        h2 t2; t2.x = (_Float16)(1.0f - tf); t2.y = (_Float16)tf;
        unsigned int src = m.x & 16383u;
        unsigned int ti  = (m.x >> 14) & 2047u;
        metaF[(size_t)g * NEDGE + p] = make_uint2((src << 6) | (ti << 20),
                                                  __builtin_bit_cast(unsigned int, t2));
    }
}

// ---------------- tabulate W_i(d)*C(d) on TK knots (fp32 scratch)
__global__ __launch_bounds__(256) void k_tables(const float* __restrict__ mw1, const float* __restrict__ mb1,
                                                const float* __restrict__ mw2, const float* __restrict__ mb2,
                                                float* __restrict__ tabf){
    int wv   = blockIdx.x * 4 + (threadIdx.x >> 6);
    int lane = threadIdx.x & 63;
    int i = wv >> 11, k = wv & (TK - 1);
    float d = (float)k * DT;
    const float step  = 10.0f / 49.0f;
    const float coeff = -0.5f / (step * step);
    float u = mb1[(i << 6) + lane];
    #pragma unroll
    for (int gg = 0; gg < NGAUSS; gg++){
        float od = d - (float)gg * step;
        float ea = __expf(coeff * od * od);
        u = fmaf(ea, mw1[((i * NGAUSS + gg) << 6) + lane], u);
    }
    float t = sspf(u);
    float w = mb2[(i << 6) + lane];
    #pragma unroll
    for (int gg = 0; gg < 64; gg++){
        float tg = __shfl(t, gg, 64);
        w = fmaf(tg, mw2[(((i << 6) + gg) << 6) + lane], w);
    }
    float cc = 0.5f * (__cosf(d * 0.31415926535897932f) + 1.0f);
    tabf[((size_t)(i * TK + k) << 6) + lane] = w * cc;
}

// ---------------- pack interleaved half2 table: tab2[k][lane] = (Wk, Wk+1)
__global__ __launch_bounds__(256) void k_pack(const float* __restrict__ tabf, __half2* __restrict__ tab2){
    size_t idx = (size_t)blockIdx.x * 256 + threadIdx.x;
    size_t rem = idx & ((size_t)TK * 64 - 1);
    float a = tabf[idx];
    float b = (rem < (size_t)TK * 64 - 64) ? tabf[idx + 64] : a;
    tab2[idx] = __floats2half2_rn(a, b);
}

// ---------------- pack 18 weight matrices transposed to fp16: wT[s][c][k] = w_s[k][c]
__global__ __launch_bounds__(256) void k_wpack(const float* __restrict__ l1w, const float* __restrict__ l2w,
                                               const float* __restrict__ l3w, __half* __restrict__ wT){
    int idx = blockIdx.x * 256 + threadIdx.x;   // < 18*4096
    int s = idx >> 12;
    int r = idx & 4095;
    int c = r >> 6, k = r & 63;
    const float* src = (s < 6) ? (l1w + s * 4096) : (s < 12 ? l2w + (s - 6) * 4096 : l3w + (s - 12) * 4096);
    wT[idx] = __float2half(src[k * 64 + c]);
}

// ---------------- agg: one wave per dst; coalesced meta load + readlane scalar meta
// per-edge math: 2 readlane (SALU-fed) + 2 gathers (uniform base + lane) + fdot2 + cvt + fma
#define PROCU(MX, MY, ACC) { \
    const __half* xp_ = xg + ((MX) & 0xFFFFF); \
    const unsigned int* tp_ = tabu + ((((unsigned int)(MX)) >> 20) << 6); \
    h2 tw_  = __builtin_bit_cast(h2, tp_[lane]); \
    h2 tf2_ = __builtin_bit_cast(h2, (unsigned int)(MY)); \
    float w_ = __builtin_amdgcn_fdot2(tw_, tf2_, 0.0f, false); \
    (ACC) = fmaf(w_, __half2float(xp_[lane]), (ACC)); }

__global__ __launch_bounds__(256) void k_agg(const __half* __restrict__ x, const __half2* __restrict__ tab2,
                                             const uint2* __restrict__ meta, const int* __restrict__ rowptr,
                                             __half* __restrict__ agg){
    // XCD partition: (blockIdx&7)<4 -> graph A, else graph G; 1 dst per wave.
    int b    = blockIdx.x;                 // < 8192
    int xcd  = b & 7;
    int slot = b >> 3;
    int g    = xcd >> 2;
    int bi   = (slot << 2) + (xcd & 3);    // [0,4096)
    int wq   = threadIdx.x >> 6;
    int lane = threadIdx.x & 63;
    int nn   = (bi << 2) + wq;             // dst atom within graph
    const int* rp = rowptr + g * (NATOMS + 1);
    int lo = rp[nn], hi = rp[nn + 1];
    const unsigned long long* mg = (const unsigned long long*)(meta + (size_t)g * NEDGE);
    const unsigned int* tabu = (const unsigned int*)tab2;
    const __half* xg = x + ((size_t)(g ? NATOMS : 0) << 6);
    float a0 = 0.f, a1 = 0.f, a2 = 0.f, a3 = 0.f;
    for (int eb = lo; eb < hi; eb += 64){
        int cnt = hi - eb; if (cnt > 64) cnt = 64;
        unsigned long long mv = 0;
        if (eb + lane < hi) mv = __builtin_nontemporal_load(&mg[eb + lane]);  // coalesced 512B
        int mlo = (int)(unsigned int)mv;
        int mhi = (int)(unsigned int)(mv >> 32);
        int j = 0;
        for (; j + 8 <= cnt; j += 8){
            int x0 = __builtin_amdgcn_readlane(mlo, j+0), y0 = __builtin_amdgcn_readlane(mhi, j+0);
            int x1 = __builtin_amdgcn_readlane(mlo, j+1), y1 = __builtin_amdgcn_readlane(mhi, j+1);
            int x2 = __builtin_amdgcn_readlane(mlo, j+2), y2 = __builtin_amdgcn_readlane(mhi, j+2);
            int x3 = __builtin_amdgcn_readlane(mlo, j+3), y3 = __builtin_amdgcn_readlane(mhi, j+3);
            int x4 = __builtin_amdgcn_readlane(mlo, j+4), y4 = __builtin_amdgcn_readlane(mhi, j+4);
            int x5 = __builtin_amdgcn_readlane(mlo, j+5), y5 = __builtin_amdgcn_readlane(mhi, j+5);
            int x6 = __builtin_amdgcn_readlane(mlo, j+6), y6 = __builtin_amdgcn_readlane(mhi, j+6);
            int x7 = __builtin_amdgcn_readlane(mlo, j+7), y7 = __builtin_amdgcn_readlane(mhi, j+7);
            PROCU(x0, y0, a0); PROCU(x1, y1, a1); PROCU(x2, y2, a2); PROCU(x3, y3, a3);
            PROCU(x4, y4, a0); PROCU(x5, y5, a1); PROCU(x6, y6, a2); PROCU(x7, y7, a3);
        }
        for (; j < cnt; j++){
            int xx = __builtin_amdgcn_readlane(mlo, j), yy = __builtin_amdgcn_readlane(mhi, j);
            PROCU(xx, yy, a0);
        }
    }
    agg[((size_t)(g * NATOMS + nn) << 6) + lane] = __float2half((a0 + a1) + (a2 + a3));
}

// ---------------- MFMA node GEMMs. mode 1: h += ssp(agg@w2+b2)@w3+b3; x = h_new@w1n
//                  mode 0: x = h @ w1n  (lin1).  Weights pre-transposed fp16 (wT).
__global__ __launch_bounds__(256) void k_updlin(const __half* __restrict__ agg, const __half* __restrict__ w2t,
                                                const float* __restrict__ b2, const __half* __restrict__ w3t,
                                                const float* __restrict__ b3, const __half* __restrict__ w1nt,
                                                float* __restrict__ h, __half* __restrict__ x,
                                                int mode, int has_x){
    __shared__ _Float16 A_lds[64 * 72];
    __shared__ _Float16 W_lds[64 * 72];
    int t = threadIdx.x;
    int w = t >> 6, lane = t & 63;
    int m = lane & 15, kg = lane >> 4;
    size_t base = (size_t)blockIdx.x * 64;

#define STAGE_W(SRC) { \
    const unsigned int* wu_ = (const unsigned int*)(SRC); \
    _Pragma("unroll") \
    for (int j = 0; j < 8; j++){ \
        int idx = j * 256 + t; \
        int row = idx >> 5, cu = idx & 31; \
        *(unsigned int*)&W_lds[row * 72 + cu * 2] = wu_[idx]; \
    } }

    // stage A
    if (mode == 1){
        const unsigned int* ag = (const unsigned int*)(agg + base * 64);
        #pragma unroll
        for (int j = 0; j < 8; j++){
            int idx = j * 256 + t;              // < 2048 u32
            int row = idx >> 5, cu = idx & 31;
            *(unsigned int*)&A_lds[row * 72 + cu * 2] = ag[idx];
        }
        STAGE_W(w2t);
    } else {
        #pragma unroll
        for (int j = 0; j < 16; j++){
            int idx = j * 256 + t;              // < 4096
            A_lds[(idx >> 6) * 72 + (idx & 63)] = (_Float16)h[base * 64 + idx];
        }
        STAGE_W(w1nt);
    }
    __syncthreads();

    int arow = (w << 4) + m;
    f32x4 acc[4];

#define GEMM_4CB() { \
    acc[0] = (f32x4)0.f; acc[1] = (f32x4)0.f; acc[2] = (f32x4)0.f; acc[3] = (f32x4)0.f; \
    _Pragma("unroll") \
    for (int kh = 0; kh < 2; kh++){ \
        f16x8 av = *(const f16x8*)&A_lds[arow * 72 + kh * 32 + kg * 8]; \
        _Pragma("unroll") \
        for (int cb = 0; cb < 4; cb++){ \
            f16x8 bv = *(const f16x8*)&W_lds[((cb << 4) + m) * 72 + kh * 32 + kg * 8]; \
            acc[cb] = __builtin_amdgcn_mfma_f32_16x16x32_f16(av, bv, acc[cb], 0, 0, 0); \
        } \
    } }

    if (mode == 0){
        GEMM_4CB();
        #pragma unroll
        for (int cb = 0; cb < 4; cb++){
            int col = (cb << 4) + m;
            #pragma unroll
            for (int v = 0; v < 4; v++){
                int row = (w << 4) + (kg << 2) + v;
                x[(base + row) * 64 + col] = __float2half(acc[cb][v]);
            }
        }
        return;
    }

    // GEMM1: t = ssp(agg @ w2 + b2)  -> A_lds
    GEMM_4CB();
    #pragma unroll
    for (int cb = 0; cb < 4; cb++){
        int col = (cb << 4) + m;
        float bv = b2[col];
        #pragma unroll
        for (int v = 0; v < 4; v++){
            int row = (w << 4) + (kg << 2) + v;
            A_lds[row * 72 + col] = (_Float16)sspf(acc[cb][v] + bv);
        }
    }
    __syncthreads();
    STAGE_W(w3t);
    __syncthreads();

    // GEMM2: h_new = t @ w3 + b3 + h  (global h update; h_new -> A_lds)
    GEMM_4CB();
    #pragma unroll
    for (int cb = 0; cb < 4; cb++){
        int col = (cb << 4) + m;
        float bv = b3[col];
        #pragma unroll
        for (int v = 0; v < 4; v++){
            int row = (w << 4) + (kg << 2) + v;
            size_t o = (base + row) * 64 + col;
            float hv = h[o] + acc[cb][v] + bv;
            h[o] = hv;
            A_lds[row * 72 + col] = (_Float16)hv;
        }
    }
    if (!has_x) return;
    __syncthreads();
    STAGE_W(w1nt);
    __syncthreads();

    // GEMM3: x = h_new @ w1_next  (fp16 out)
    GEMM_4CB();
    #pragma unroll
    for (int cb = 0; cb < 4; cb++){
        int col = (cb << 4) + m;
        #pragma unroll
        for (int v = 0; v < 4; v++){
            int row = (w << 4) + (kg << 2) + v;
            x[(base + row) * 64 + col] = __float2half(acc[cb][v]);
        }
    }
#undef GEMM_4CB
#undef STAGE_W
}

// ---------------- readout: eout[g][f] = sum_n h[n][f]
__global__ __launch_bounds__(256) void k_readout(const float* __restrict__ h, float* __restrict__ eout){
    int f  = threadIdx.x & 63;
    int wq = threadIdx.x >> 6;
    int nodeBase = blockIdx.x * 256 + wq * 64;
    float acc = 0.f;
    #pragma unroll 4
    for (int j = 0; j < 64; j++) acc += h[(size_t)(nodeBase + j) * 64 + f];
    int g = nodeBase >= NATOMS;
    atomicAdd(&eout[g * 64 + f], acc);
}

// ---------------- head: fc1 -> PReLU -> fc2 -> exp
__global__ __launch_bounds__(64) void k_final(const float* __restrict__ eout, const float* __restrict__ addf,
                                              const float* __restrict__ fc1w, const float* __restrict__ fc1b,
                                              const float* __restrict__ pra, const float* __restrict__ fc2w,
                                              const float* __restrict__ fc2b, float* __restrict__ out){
    int f = threadIdx.x;
    float xv = fc1b[f];
    const float inv = 1.0f / 256.0f;
    for (int k = 0; k < 64; k++)  xv = fmaf(eout[k] * inv,      fc1w[k * 64 + f],        xv);
    for (int k = 0; k < 64; k++)  xv = fmaf(eout[64 + k] * inv, fc1w[(64 + k) * 64 + f], xv);
    xv = fmaf(addf[0], fc1w[128 * 64 + f], xv);
    xv = fmaf(addf[1], fc1w[129 * 64 + f], xv);
    float a = pra[0];
    xv = (xv >= 0.f) ? xv : a * xv;
    float s = xv * fc2w[f];
    #pragma unroll
    for (int m = 32; m >= 1; m >>= 1) s += __shfl_xor(s, m, 64);
    if (f == 0) out[0] = expf(s + fc2b[0]);
}

extern "C" void kernel_launch(void* const* d_in, const int* in_sizes, int n_in,
                              void* d_out, int out_size, void* d_ws, size_t ws_size,
                              hipStream_t stream){
    const int*   zA    = (const int*)  d_in[0];
    const float* posA  = (const float*)d_in[1];
    const int*   edgeA = (const int*)  d_in[3];
    const int*   zG    = (const int*)  d_in[4];
    const float* posG  = (const float*)d_in[5];
    const int*   edgeG = (const int*)  d_in[7];
    const float* addf  = (const float*)d_in[8];
    const float* emb   = (const float*)d_in[9];
    const float* mw1   = (const float*)d_in[10];
    const float* mb1   = (const float*)d_in[11];
    const float* mw2   = (const float*)d_in[12];
    const float* mb2   = (const float*)d_in[13];
    const float* l1w   = (const float*)d_in[14];
    const float* l2w   = (const float*)d_in[15];
    const float* l2b   = (const float*)d_in[16];
    const float* l3w   = (const float*)d_in[17];
    const float* l3b   = (const float*)d_in[18];
    const float* fc1w  = (const float*)d_in[19];
    const float* fc1b  = (const float*)d_in[20];
    const float* pra   = (const float*)d_in[21];
    const float* fc2w  = (const float*)d_in[22];
    const float* fc2b  = (const float*)d_in[23];
    float* out = (float*)d_out;

    // workspace layout (~42 MB)
    char* p = (char*)d_ws;
    auto alloc = [&](size_t bytes)->char*{ char* r = p; p += (bytes + 255) & ~(size_t)255; return r; };
    float*   tabf   = (float*)  alloc((size_t)NINT * TK * 64 * 4);   // 3.1 MB
    __half2* tab2   = (__half2*)alloc((size_t)NINT * TK * 64 * 4);   // 3.1 MB
    uint2*   meta8  = (uint2*)  alloc((size_t)2 * NEDGE * 8);        // 8.4 MB
    uint2*   metaF  = (uint2*)  alloc((size_t)2 * NEDGE * 8);        // 8.4 MB
    int*     rowptr = (int*)    alloc((size_t)2 * (NATOMS + 1) * 4);
    int*     gcur   = (int*)    alloc((size_t)2 * NBUCK * 4);
    int*     bhist  = (int*)    alloc((size_t)2 * NBUCK * 4);
    int*     bstart = (int*)    alloc((size_t)2 * (NBUCK + 1) * 4);
    float*   h      = (float*)  alloc((size_t)2 * NATOMS * 64 * 4);  // 8.4 MB
    __half*  x      = (__half*) alloc((size_t)2 * NATOMS * 64 * 2);  // 4.2 MB
    __half*  agg    = (__half*) alloc((size_t)2 * NATOMS * 64 * 2);  // 4.2 MB
    __half*  wT     = (__half*) alloc((size_t)18 * 4096 * 2);        // 147 KB
    float*   eout   = (float*)  alloc(128 * 4);

    hipMemsetAsync(bhist, 0, (size_t)2 * NBUCK * 4, stream);
    hipMemsetAsync(eout, 0, 128 * 4, stream);

    k_embed <<<(2 * NATOMS * 64) / 256, 256, 0, stream>>>(zA, zG, emb, h);
    k_bhist <<<256, 256, 0, stream>>>(edgeA, edgeG, bhist);
    k_bscan <<<2, 512, 0, stream>>>(bhist, bstart, gcur);
    k_place1<<<256,  256, 0, stream>>>(edgeA, edgeG, posA, posG, gcur, meta8);
    k_place2<<<1024, 256, 0, stream>>>(meta8, bstart, rowptr, metaF);
    k_tables<<<(NINT * TK) / 4,        256, 0, stream>>>(mw1, mb1, mw2, mb2, tabf);
    k_pack  <<<(NINT * TK * 64) / 256, 256, 0, stream>>>(tabf, tab2);
    k_wpack <<<(18 * 4096) / 256,      256, 0, stream>>>(l1w, l2w, l3w, wT);

    const __half* w1t0 = wT;
    // lin1 (mode 0)
    k_updlin<<<(2 * NATOMS) / 64, 256, 0, stream>>>(agg, wT, l2b, wT, l3b, w1t0, h, x, 0, 1);
    for (int i = 0; i < NINT; i++){
        k_agg<<<(2 * NATOMS) / 4, 256, 0, stream>>>(x, tab2 + (size_t)i * TK * 64, metaF, rowptr, agg);
        int has_x = (i < NINT - 1);
        const __half* w2t  = wT + (size_t)(6 + i) * 4096;
        const __half* w3t  = wT + (size_t)(12 + i) * 4096;
        const __half* w1nt = wT + (size_t)(has_x ? (i + 1) : 0) * 4096;
        k_updlin<<<(2 * NATOMS) / 64, 256, 0, stream>>>(agg, w2t, l2b + i * 64,
                                                        w3t, l3b + i * 64, w1nt, h, x, 1, has_x);
    }

    k_readout<<<(2 * NATOMS) / 256, 256, 0, stream>>>(h, eout);
    k_final  <<<1, 64, 0, stream>>>(eout, addf, fc1w, fc1b, pra, fc2w, fc2b, out);
}